// Round 7
// baseline (101.396 us; speedup 1.0000x reference)
//
#include <hip/hip_runtime.h>
#include <math.h>

constexpr int H = 2048;
constexpr int W = 4096;
constexpr int RS = W * 3;   // floats per image row

// Keys cubic (a = -0.5) pieces on known-positive argument.
__device__ __forceinline__ float k_inner(float t) {   // t in [0,1]:  1.5t^3 - 2.5t^2 + 1
    return fmaf(fmaf(1.5f, t, -2.5f), t * t, 1.0f);
}
__device__ __forceinline__ float k_outer(float t) {   // t in [1,2]: -0.5t^3 + 2.5t^2 - 4t + 2
    return fmaf(fmaf(fmaf(-0.5f, t, 2.5f), t, -4.0f), t, 2.0f);
}
__device__ __forceinline__ float cubic_w(float t) {
    float at = fabsf(t);
    if (at <= 1.0f) return k_inner(at);
    if (at < 2.0f)  return k_outer(at);
    return 0.0f;
}

// general clamped 16-tap gather for one pixel (slow path)
__device__ __forceinline__ void gather_px(const float* __restrict__ img,
                                          int iy, int ix,
                                          const float wy[4], const float wx[4],
                                          float& o0, float& o1, float& o2) {
    o0 = 0.f; o1 = 0.f; o2 = 0.f;
#pragma unroll
    for (int a = 0; a < 4; ++a) {
        int ty = iy + a - 1;
        ty = ty < 0 ? 0 : (ty > H - 1 ? H - 1 : ty);
        int rowoff = ty * RS;
        float ay = wy[a];
#pragma unroll
        for (int b = 0; b < 4; ++b) {
            int tx = ix + b - 1;
            tx = tx < 0 ? 0 : (tx > W - 1 ? W - 1 : tx);
            float wgt = ay * wx[b];
            const float* p = img + rowoff + tx * 3;
            o0 += wgt * p[0];
            o1 += wgt * p[1];
            o2 += wgt * p[2];
        }
    }
}

__global__ __launch_bounds__(256)
void elastic_warp_kernel(const float* __restrict__ img,
                         const float* __restrict__ dctrl,  // (2,3,3) unscaled
                         float* __restrict__ out) {
    // Block: 512 consecutive px of ONE row; each thread owns 2 consecutive px.
    int h  = blockIdx.x >> 3;                                  // W/512 = 8 x-tiles
    int x0 = ((blockIdx.x & 7) << 9) | ((int)threadIdx.x << 1);

    // ---- block-uniform: cy = 5 * (by^T . D) ----
    __shared__ float s_cy[6];
    if (threadIdx.x == 0) {
        float u = (float)(2 * h) / (float)(H - 1);
        float i0 = floorf(u);
        float by0 = 0.f, by1 = 0.f, by2 = 0.f;
#pragma unroll
        for (int k = -1; k < 3; ++k) {
            float tap = i0 + (float)k;
            float wt = cubic_w(u - tap);
            int tc = (int)tap;
            tc = tc < 0 ? 0 : (tc > 2 ? 2 : tc);
            if (tc == 0) by0 += wt; else if (tc == 1) by1 += wt; else by2 += wt;
        }
#pragma unroll
        for (int x = 0; x < 3; ++x) {
            s_cy[x]     = 5.0f * (by0 * dctrl[x]     + by1 * dctrl[3 + x]  + by2 * dctrl[6 + x]);
            s_cy[3 + x] = 5.0f * (by0 * dctrl[9 + x] + by1 * dctrl[12 + x] + by2 * dctrl[15 + x]);
        }
    }
    __syncthreads();
    float cy0 = s_cy[0], cy1 = s_cy[1], cy2 = s_cy[2];
    float cy3 = s_cy[3], cy4 = s_cy[4], cy5 = s_cy[5];

    // ---- per-px spline bx -> displacement, for x0 and x0+1 ----
    float d0[2], d1[2];
#pragma unroll
    for (int p = 0; p < 2; ++p) {
        float u = (float)(x0 + p) * (2.0f / 4095.0f);
        bool hiu = u >= 1.0f;
        float s = u - (hiu ? 1.0f : 0.0f);
        float o1v = k_outer(1.0f + s);
        float isv = k_inner(s);
        float i1v = k_inner(1.0f - s);
        float o2v = k_outer(2.0f - s);
        float bx0 = hiu ? o1v : (o1v + isv);
        float bx1 = hiu ? isv : i1v;
        float bx2 = hiu ? (i1v + o2v) : o2v;
        d0[p] = cy0 * bx0 + cy1 * bx1 + cy2 * bx2;
        d1[p] = cy3 * bx0 + cy4 * bx1 + cy5 * bx2;
    }

    // ---- coords + tap weights for both pixels ----
    float yy0 = (float)h + d0[0],  xx0 = (float)x0 + d1[0];
    float yy1 = (float)h + d0[1],  xx1 = (float)(x0 + 1) + d1[1];
    float fly0 = floorf(yy0), flx0 = floorf(xx0);
    float fly1 = floorf(yy1), flx1 = floorf(xx1);
    float fy0 = yy0 - fly0, fx0 = xx0 - flx0;
    float fy1 = yy1 - fly1, fx1 = xx1 - flx1;
    int iy0 = (int)fly0, ix0 = (int)flx0;
    int iy1 = (int)fly1, ix1 = (int)flx1;

    float wy0[4] = {k_outer(1.f + fy0), k_inner(fy0), k_inner(1.f - fy0), k_outer(2.f - fy0)};
    float wx0[4] = {k_outer(1.f + fx0), k_inner(fx0), k_inner(1.f - fx0), k_outer(2.f - fx0)};
    float wy1[4] = {k_outer(1.f + fy1), k_inner(fy1), k_inner(1.f - fy1), k_outer(2.f - fy1)};
    float wx1[4] = {k_outer(1.f + fx1), k_inner(fx1), k_inner(1.f - fx1), k_outer(2.f - fx1)};

    float a0, a1, a2, b0, b1, b2;   // outputs px0, px1

    int e  = ix1 - ix0;        // expected in {0,1,2}
    int f1 = iy1 - iy0 + 1;    // expected in {0,1,2}
    bool fast = (iy0 >= 2) & (iy0 <= H - 4) & (ix0 >= 1) & (ix0 <= W - 5) &
                (e >= 0) & (e <= 2) & (f1 >= 0) & (f1 <= 2);

    if (__all(fast)) {
        int br = iy0 - 2;          // staged rows br..br+5
        int bc3 = (ix0 - 1) * 3;   // staged cols ix0-1..ix0+4 (18 floats/row)

        // scatter px1's x-weights into dense 6-wide (shift by e)
        bool e0 = (e == 0), e1 = (e == 1);
        float wx1d[6];
        wx1d[0] = e0 ? wx1[0] : 0.f;
        wx1d[1] = e0 ? wx1[1] : (e1 ? wx1[0] : 0.f);
        wx1d[2] = e0 ? wx1[2] : (e1 ? wx1[1] : wx1[0]);
        wx1d[3] = e0 ? wx1[3] : (e1 ? wx1[2] : wx1[1]);
        wx1d[4] = e0 ? 0.f    : (e1 ? wx1[3] : wx1[2]);
        wx1d[5] = (!e0 && !e1) ? wx1[3] : 0.f;

        // scatter px1's y-weights into dense 6-row (shift by f1)
        bool f0 = (f1 == 0), fo = (f1 == 1);
        float wr1[6];
        wr1[0] = f0 ? wy1[0] : 0.f;
        wr1[1] = f0 ? wy1[1] : (fo ? wy1[0] : 0.f);
        wr1[2] = f0 ? wy1[2] : (fo ? wy1[1] : wy1[0]);
        wr1[3] = f0 ? wy1[3] : (fo ? wy1[2] : wy1[1]);
        wr1[4] = f0 ? 0.f    : (fo ? wy1[3] : wy1[2]);
        wr1[5] = (!f0 && !fo) ? wy1[3] : 0.f;

        a0 = a1 = a2 = 0.f;
        b0 = b1 = b2 = 0.f;

#pragma unroll
        for (int r = 0; r < 6; ++r) {
            const float* rp = img + (br + r) * RS + bc3;
            float4 A = *(const float4*)(rp);
            float4 B = *(const float4*)(rp + 4);
            float4 Cc = *(const float4*)(rp + 8);
            float4 E = *(const float4*)(rp + 12);
            float2 Dd = *(const float2*)(rp + 16);
            float v0 = A.x,  v1 = A.y,  v2 = A.z,  v3 = A.w;
            float v4 = B.x,  v5 = B.y,  v6 = B.z,  v7 = B.w;
            float v8 = Cc.x, v9 = Cc.y, v10 = Cc.z, v11 = Cc.w;
            float v12 = E.x, v13 = E.y, v14 = E.z, v15 = E.w;
            float v16 = Dd.x, v17 = Dd.y;

            // px1: dense 6-tap row
            float s0 = fmaf(wx1d[0], v0,  fmaf(wx1d[1], v3,  fmaf(wx1d[2], v6,
                       fmaf(wx1d[3], v9,  fmaf(wx1d[4], v12, wx1d[5] * v15)))));
            float s1 = fmaf(wx1d[0], v1,  fmaf(wx1d[1], v4,  fmaf(wx1d[2], v7,
                       fmaf(wx1d[3], v10, fmaf(wx1d[4], v13, wx1d[5] * v16)))));
            float s2 = fmaf(wx1d[0], v2,  fmaf(wx1d[1], v5,  fmaf(wx1d[2], v8,
                       fmaf(wx1d[3], v11, fmaf(wx1d[4], v14, wx1d[5] * v17)))));
            b0 = fmaf(wr1[r], s0, b0);
            b1 = fmaf(wr1[r], s1, b1);
            b2 = fmaf(wr1[r], s2, b2);

            // px0: exact 4-tap at static rows 1..4, static cols 0..3
            if (r >= 1 && r <= 4) {
                float t0 = fmaf(wx0[0], v0, fmaf(wx0[1], v3, fmaf(wx0[2], v6,  wx0[3] * v9)));
                float t1 = fmaf(wx0[0], v1, fmaf(wx0[1], v4, fmaf(wx0[2], v7,  wx0[3] * v10)));
                float t2 = fmaf(wx0[0], v2, fmaf(wx0[1], v5, fmaf(wx0[2], v8,  wx0[3] * v11)));
                float ay = wy0[r - 1];
                a0 = fmaf(ay, t0, a0);
                a1 = fmaf(ay, t1, a1);
                a2 = fmaf(ay, t2, a2);
            }
        }
    } else {
        gather_px(img, iy0, ix0, wy0, wx0, a0, a1, a2);
        gather_px(img, iy1, ix1, wy1, wx1, b0, b1, b2);
    }

    int oo = (h * W + x0) * 3;
    float2 w01 = {a0, a1};
    float2 w23 = {a2, b0};
    float2 w45 = {b1, b2};
    *(float2*)(out + oo)     = w01;
    *(float2*)(out + oo + 2) = w23;
    *(float2*)(out + oo + 4) = w45;
}

extern "C" void kernel_launch(void* const* d_in, const int* in_sizes, int n_in,
                              void* d_out, int out_size, void* d_ws, size_t ws_size,
                              hipStream_t stream) {
    const float* img   = (const float*)d_in[0];
    const float* dctrl = (const float*)d_in[1];
    float* out = (float*)d_out;

    int blocks = H * (W / 512);   // 2 px per thread, 512 px per block
    elastic_warp_kernel<<<blocks, 256, 0, stream>>>(img, dctrl, out);
}

// Round 8
// 64.553 us; speedup vs baseline: 1.5707x; 1.5707x over previous
//
#include <hip/hip_runtime.h>
#include <math.h>

constexpr int H = 2048;
constexpr int W = 4096;
constexpr int RS = W * 3;   // floats per image row

// Keys cubic (a = -0.5) pieces on known-positive argument.
__device__ __forceinline__ float k_inner(float t) {   // t in [0,1]:  1.5t^3 - 2.5t^2 + 1
    return fmaf(fmaf(1.5f, t, -2.5f), t * t, 1.0f);
}
__device__ __forceinline__ float k_outer(float t) {   // t in [1,2]: -0.5t^3 + 2.5t^2 - 4t + 2
    return fmaf(fmaf(fmaf(-0.5f, t, 2.5f), t, -4.0f), t, 2.0f);
}
__device__ __forceinline__ float cubic_w(float t) {
    float at = fabsf(t);
    if (at <= 1.0f) return k_inner(at);
    if (at < 2.0f)  return k_outer(at);
    return 0.0f;
}

// Block = 16x16 pixel tile. Wave w covers rows 4w..4w+3 of the tile, 16 px each.
// Lane layout: xi = lane&15 (column), gi = lane>>4 (row within wave's 4 rows).
// => one wave-level gather instruction spans 4 image-row segments of ~19 px
//    (~16 cache lines) instead of one 259-px segment (~48 lines): 3x less L1 work.
__global__ __launch_bounds__(256)
void elastic_warp_kernel(const float* __restrict__ img,
                         const float* __restrict__ dctrl,  // (2,3,3) unscaled
                         float* __restrict__ out) {
    int x0 = blockIdx.x << 4;
    int y0 = blockIdx.y << 4;

    int t = threadIdx.x;
    int lane = t & 63;
    int wave = t >> 6;
    int xi = lane & 15;
    int gi = lane >> 4;
    int r  = (wave << 2) + gi;     // row within tile, 0..15

    int h = y0 + r;
    int w = x0 + xi;

    // ---- per-tile-row uniform: cy = 5 * (by^T . D), for the 16 rows ----
    __shared__ float s_cy[16][6];
    if (t < 16) {
        int hh = y0 + t;
        float u = (float)(2 * hh) / (float)(H - 1);
        float i0 = floorf(u);
        float by0 = 0.f, by1 = 0.f, by2 = 0.f;
#pragma unroll
        for (int k = -1; k < 3; ++k) {
            float tap = i0 + (float)k;
            float wt = cubic_w(u - tap);
            int tc = (int)tap;
            tc = tc < 0 ? 0 : (tc > 2 ? 2 : tc);
            if (tc == 0) by0 += wt; else if (tc == 1) by1 += wt; else by2 += wt;
        }
#pragma unroll
        for (int x = 0; x < 3; ++x) {
            s_cy[t][x]     = 5.0f * (by0 * dctrl[x]     + by1 * dctrl[3 + x]  + by2 * dctrl[6 + x]);
            s_cy[t][3 + x] = 5.0f * (by0 * dctrl[9 + x] + by1 * dctrl[12 + x] + by2 * dctrl[15 + x]);
        }
    }
    __syncthreads();

    float cy0 = s_cy[r][0], cy1 = s_cy[r][1], cy2 = s_cy[r][2];
    float cy3 = s_cy[r][3], cy4 = s_cy[r][4], cy5 = s_cy[r][5];

    // ---- per-thread bx[3] (piecewise, branchless) ----
    float u = (float)w * (2.0f / 4095.0f);
    bool hiu = u >= 1.0f;
    float s = u - (hiu ? 1.0f : 0.0f);
    float o1 = k_outer(1.0f + s);
    float is = k_inner(s);
    float i1 = k_inner(1.0f - s);
    float o2 = k_outer(2.0f - s);
    float bx0 = hiu ? o1 : (o1 + is);
    float bx1 = hiu ? is : i1;
    float bx2 = hiu ? (i1 + o2) : o2;

    float d0 = cy0 * bx0 + cy1 * bx1 + cy2 * bx2;
    float d1 = cy3 * bx0 + cy4 * bx1 + cy5 * bx2;

    // ---- sample coordinates ----
    float yy = (float)h + d0;
    float xx = (float)w + d1;
    float iy0f = floorf(yy);
    float ix0f = floorf(xx);
    float fy = yy - iy0f;
    float fx = xx - ix0f;
    int iy0 = (int)iy0f;
    int ix0 = (int)ix0f;

    float wy0 = k_outer(1.0f + fy), wy1 = k_inner(fy), wy2 = k_inner(1.0f - fy), wy3 = k_outer(2.0f - fy);
    float wx0 = k_outer(1.0f + fx), wx1 = k_inner(fx), wx2 = k_inner(1.0f - fx), wx3 = k_outer(2.0f - fx);

    float acc0 = 0.0f, acc1 = 0.0f, acc2 = 0.0f;

    bool interior = (iy0 >= 1) & (iy0 <= H - 3) & (ix0 >= 1) & (ix0 <= W - 3);
    if (interior) {
        int off = ((iy0 - 1) * W + (ix0 - 1)) * 3;
        const float* b0 = img + off;
        const float* b1 = b0 + RS;
        const float* b2 = b1 + RS;
        const float* b3 = b2 + RS;

        float4 v00 = ((const float4*)b0)[0];
        float4 v01 = ((const float4*)b0)[1];
        float4 v02 = ((const float4*)b0)[2];
        float4 v10 = ((const float4*)b1)[0];
        float4 v11 = ((const float4*)b1)[1];
        float4 v12 = ((const float4*)b1)[2];
        float4 v20 = ((const float4*)b2)[0];
        float4 v21 = ((const float4*)b2)[1];
        float4 v22 = ((const float4*)b2)[2];
        float4 v30 = ((const float4*)b3)[0];
        float4 v31 = ((const float4*)b3)[1];
        float4 v32 = ((const float4*)b3)[2];

        float q0, q1, q2, q3;
        q0 = wy0 * wx0; q1 = wy0 * wx1; q2 = wy0 * wx2; q3 = wy0 * wx3;
        acc0 = fmaf(q0, v00.x, fmaf(q1, v00.w, fmaf(q2, v01.z, fmaf(q3, v02.y, acc0))));
        acc1 = fmaf(q0, v00.y, fmaf(q1, v01.x, fmaf(q2, v01.w, fmaf(q3, v02.z, acc1))));
        acc2 = fmaf(q0, v00.z, fmaf(q1, v01.y, fmaf(q2, v02.x, fmaf(q3, v02.w, acc2))));

        q0 = wy1 * wx0; q1 = wy1 * wx1; q2 = wy1 * wx2; q3 = wy1 * wx3;
        acc0 = fmaf(q0, v10.x, fmaf(q1, v10.w, fmaf(q2, v11.z, fmaf(q3, v12.y, acc0))));
        acc1 = fmaf(q0, v10.y, fmaf(q1, v11.x, fmaf(q2, v11.w, fmaf(q3, v12.z, acc1))));
        acc2 = fmaf(q0, v10.z, fmaf(q1, v11.y, fmaf(q2, v12.x, fmaf(q3, v12.w, acc2))));

        q0 = wy2 * wx0; q1 = wy2 * wx1; q2 = wy2 * wx2; q3 = wy2 * wx3;
        acc0 = fmaf(q0, v20.x, fmaf(q1, v20.w, fmaf(q2, v21.z, fmaf(q3, v22.y, acc0))));
        acc1 = fmaf(q0, v20.y, fmaf(q1, v21.x, fmaf(q2, v21.w, fmaf(q3, v22.z, acc1))));
        acc2 = fmaf(q0, v20.z, fmaf(q1, v21.y, fmaf(q2, v22.x, fmaf(q3, v22.w, acc2))));

        q0 = wy3 * wx0; q1 = wy3 * wx1; q2 = wy3 * wx2; q3 = wy3 * wx3;
        acc0 = fmaf(q0, v30.x, fmaf(q1, v30.w, fmaf(q2, v31.z, fmaf(q3, v32.y, acc0))));
        acc1 = fmaf(q0, v30.y, fmaf(q1, v31.x, fmaf(q2, v31.w, fmaf(q3, v32.z, acc1))));
        acc2 = fmaf(q0, v30.z, fmaf(q1, v31.y, fmaf(q2, v32.x, fmaf(q3, v32.w, acc2))));
    } else {
        float wy[4] = {wy0, wy1, wy2, wy3};
        float wx[4] = {wx0, wx1, wx2, wx3};
#pragma unroll
        for (int a = 0; a < 4; ++a) {
            int ty = iy0 + a - 1;
            ty = ty < 0 ? 0 : (ty > H - 1 ? H - 1 : ty);
            int rowoff = ty * RS;
            float ay = wy[a];
#pragma unroll
            for (int b = 0; b < 4; ++b) {
                int tx = ix0 + b - 1;
                tx = tx < 0 ? 0 : (tx > W - 1 ? W - 1 : tx);
                float wgt = ay * wx[b];
                const float* p = img + rowoff + tx * 3;
                acc0 += wgt * p[0];
                acc1 += wgt * p[1];
                acc2 += wgt * p[2];
            }
        }
    }

    int oo = (h * W + w) * 3;
    out[oo + 0] = acc0;
    out[oo + 1] = acc1;
    out[oo + 2] = acc2;
}

extern "C" void kernel_launch(void* const* d_in, const int* in_sizes, int n_in,
                              void* d_out, int out_size, void* d_ws, size_t ws_size,
                              hipStream_t stream) {
    const float* img   = (const float*)d_in[0];
    const float* dctrl = (const float*)d_in[1];
    float* out = (float*)d_out;

    dim3 grid(W / 16, H / 16);
    elastic_warp_kernel<<<grid, 256, 0, stream>>>(img, dctrl, out);
}